// Round 8
// baseline (321.786 us; speedup 1.0000x reference)
//
#include <hip/hip_runtime.h>

// Problem constants (B, LQ, LK, D from the reference)
#define B_  8
#define LQ_ 2048
#define LK_ 2048
#define D_  1024

typedef unsigned short u16;
using short8  = __attribute__((ext_vector_type(8))) short;   // 8 bf16 = 4 VGPRs (MFMA A/B frag)
using floatx4 = __attribute__((ext_vector_type(4))) float;   // MFMA C/D frag

#define GAS __attribute__((address_space(1)))
#define LAS __attribute__((address_space(3)))

__device__ __forceinline__ u16 f2bf(float f) {
  unsigned u = __float_as_uint(f);
  u += 0x7fffu + ((u >> 16) & 1u);   // round-to-nearest-even
  return (u16)(u >> 16);
}
__device__ __forceinline__ float bf2f(u16 h) {
  return __uint_as_float(((unsigned)h) << 16);
}

// ---------------------------------------------------------------------------
// prep (unchanged)
// ---------------------------------------------------------------------------
__global__ void prep(const float* __restrict__ in, const float* __restrict__ mem,
                     const float* __restrict__ ds, u16* __restrict__ qb,
                     u16* __restrict__ mb, u16* __restrict__ mbT,
                     float* __restrict__ denom) {
  __shared__ u16 tile[64][68];
  int tid = threadIdx.x;
  int tx = tid & 15, ty = tid >> 4;
  int b = blockIdx.z;

  if (denom && blockIdx.y == 16 && blockIdx.x == 0 && blockIdx.z == 0) {
    float4 z = {0.f, 0.f, 0.f, 0.f};
    float4* d4 = (float4*)denom;
#pragma unroll
    for (int i = 0; i < (B_ * LQ_ / 4) / 256; i++)
      d4[tid + i * 256] = z;
  }

  if (blockIdx.y < 16) {
    int k0 = blockIdx.x * 64, d0 = blockIdx.y * 64;
    const float* mB = mem + (size_t)b * LK_ * D_;
    u16* mbB = mb  + (size_t)b * LK_ * D_;
    u16* mtB = mbT + (size_t)b * D_ * LK_;
#pragma unroll
    for (int i = 0; i < 4; i++) {
      int r = ty + 16 * i;
      float4 v = *(const float4*)(mB + (size_t)(k0 + r) * D_ + d0 + tx * 4);
      ushort4 h;
      h.x = f2bf(v.x); h.y = f2bf(v.y); h.z = f2bf(v.z); h.w = f2bf(v.w);
      *(ushort4*)(mbB + (size_t)(k0 + r) * D_ + d0 + tx * 4) = h;
      *(ushort4*)(&tile[r][tx * 4]) = h;
    }
    __syncthreads();
#pragma unroll
    for (int i = 0; i < 4; i++) {
      int rr = ty + 16 * i;
      ushort4 o;
      o.x = tile[tx * 4 + 0][rr];
      o.y = tile[tx * 4 + 1][rr];
      o.z = tile[tx * 4 + 2][rr];
      o.w = tile[tx * 4 + 3][rr];
      *(ushort4*)(mtB + (size_t)(d0 + rr) * LK_ + k0 + tx * 4) = o;
    }
  } else {
    int q0 = blockIdx.x * 64, d0 = (blockIdx.y - 16) * 64;
    const float* iB = in + (size_t)b * LQ_ * D_;
    u16* qB = qb + (size_t)b * LQ_ * D_;
    float4 s4 = *(const float4*)(ds + d0 + tx * 4);
#pragma unroll
    for (int i = 0; i < 4; i++) {
      int r = ty + 16 * i;
      float4 v = *(const float4*)(iB + (size_t)(q0 + r) * D_ + d0 + tx * 4);
      ushort4 h;
      h.x = f2bf(v.x * s4.x); h.y = f2bf(v.y * s4.y);
      h.z = f2bf(v.z * s4.z); h.w = f2bf(v.w * s4.w);
      *(ushort4*)(qB + (size_t)(q0 + r) * D_ + d0 + tx * 4) = h;
    }
  }
}

// ---------------------------------------------------------------------------
// gemm_bt: C[M,N] = A[M,K] * B[N,K]^T per batch.
// Geometry: 256x256 tile, BK=64, 8 waves (2M x 4N), wave tile 128x64,
//   acc[8][4] 16x16x32 frags (AGPRs). LDS per matrix [2 buf][256 r][64 k]
//   bf16 = 32 KiB/buf (128 KiB total). XOR swizzle (proven 0-conflict):
//   16B chunk (row, sl) holds global k-chunk sl^(row&7); applied to the
//   global SOURCE of global_load_lds (LDS dest linear) + ds_read addr.
// SCHEDULE v7b (queue-balanced 8-phase pipeline, DE-RISKED):
//   v7's cross-buffer Ph6/7 prefetch (reads straddling a B1/B2 barrier
//   pair) is the prime suspect for the round-6/7 container deaths (hang):
//   counted lgkm waits interleaved with barriers are fragile against
//   compiler-inserted lgkm ops. v7b removes it — single barrier per tile,
//   all fragment reads from the CURRENT buffer only (the round-5-passing
//   sync pattern), keeping the queue-balance lesson: <=4 ds_reads +
//   <=2 stage loads per phase vs 8 MFMA (DS ~385cy/CU vs MFMA ~310cy/SIMD).
//   Per-wave lgkm ledger (steady tile; counted waits verified):
//     top:  +afE(4) +bfL(4)                  -> 8 pending
//     Ph0:  +bfR(4) [stg A01] LG(4)=afE,bfL  -> MFMA(m01,L)
//     Ph1:  +afO(4) [stg A23] LG(4)=bfR      -> MFMA(m01,R)
//     Ph2:  +afE'(4)[stg B01] LG(4)=afO      -> MFMA(m23,L)
//     Ph3:          [stg B23]                -> MFMA(m23,R)
//     Ph4:  +afO'(4)          LG(4)=afE'     -> MFMA(m45,L)
//     Ph5:                                   -> MFMA(m45,R)
//     Ph6:                    LG(0)=afO'     -> MFMA(m67,L)
//     Ph7:                                   -> MFMA(m67,R)
//     VM0 (t+1 stages resident); s_barrier
//   SAFETY: reads only cur, stages only nb; Ph6's LG(0) drains every read
//   before the tile-end barrier, so next tile's stages (into old cur)
//   cannot race a straggler's reads. One barrier/tile bounds skew.
//   Last tile: no stages; VM0 trivially satisfied.
// MODE 1: score GEMM; E=exp(s) bf16 (masked->0) + atomic denom row sums.
// MODE 0: out GEMM; divides by denom[row], stores f32.
// MODE 2: fallback (in-loop rowsum from A banks at their first-use phase).
// ---------------------------------------------------------------------------
template <int MODE>
__global__ __launch_bounds__(512, 2) void gemm_bt(
    const u16* __restrict__ A, const u16* __restrict__ Bm,
    void* __restrict__ C, const float* __restrict__ mask,
    float* __restrict__ denom, int K, int ld, int ldc,
    size_t sA, size_t sB, size_t sC) {
  __shared__ __align__(16) u16 As[2 * 16384];   // [buf][256][64] u16, 64 KiB
  __shared__ __align__(16) u16 Bs[2 * 16384];

  const int tid = threadIdx.x;
  const int lane = tid & 63, w = tid >> 6;
  const int lm = lane & 15, quad = (lane >> 4) & 3;
  const int wm = (w >> 2) * 128, wn = (w & 3) * 64;

  // ---- swizzle: batch = bid&7 (XCD affinity), GM=4 m-groups, n-fast ----
  const int tiles_n = gridDim.x;
  int bid = (blockIdx.z * gridDim.y + blockIdx.y) * tiles_n + blockIdx.x;
  int bz = bid & 7;
  int s = bid >> 3;
  const int GM = 4;
  int per_group = GM * tiles_n;
  int group = s / per_group;
  int rem = s - group * per_group;
  int tm = group * GM + (rem & (GM - 1));
  int tn = rem >> 2;

  const u16* Ab = A  + (size_t)bz * sA + (size_t)(tm * 256) * ld;
  const u16* Bb = Bm + (size_t)bz * sB + (size_t)(tn * 256) * ld;

  // ---- staging: 2048 16B-chunks per matrix per tile; thread covers
  // c = tid + 512j, j=0..3. rho=c>>3 (row), sl=c&7 (slot). LDS dest linear;
  // global source pre-swizzled: k-chunk = sl ^ (rho&7).
  int goff[4], lofs[4];
#pragma unroll
  for (int j = 0; j < 4; j++) {
    int c = tid + 512 * j;
    int rho = c >> 3, sl = c & 7;
    goff[j] = rho * ld + (sl ^ (rho & 7)) * 8;   // elements
    lofs[j] = c * 8;                              // elements
  }

  // stage a 2-chunk granule (j = J0, J0+1) of A or B into buf at k0
#define STG_A(BUF, K0, J0)                                                    \
  { _Pragma("unroll")                                                         \
    for (int j = (J0); j < (J0) + 2; j++)                                     \
      __builtin_amdgcn_global_load_lds((GAS void*)(Ab + goff[j] + (K0)),      \
          (LAS void*)(As + (BUF) * 16384 + lofs[j]), 16, 0, 0); }
#define STG_B(BUF, K0, J0)                                                    \
  { _Pragma("unroll")                                                         \
    for (int j = (J0); j < (J0) + 2; j++)                                     \
      __builtin_amdgcn_global_load_lds((GAS void*)(Bb + goff[j] + (K0)),      \
          (LAS void*)(Bs + (BUF) * 16384 + lofs[j]), 16, 0, 0); }

  // ---- fragment reads: logical k-chunk (ks*4+quad) at row (base16+lm),
  // swizzled slot = chunk ^ (lm&7) (row&7 == lm&7).
  const int ka0 = ((0 + quad) ^ (lm & 7)) * 8;
  const int ka1 = ((4 + quad) ^ (lm & 7)) * 8;

  short8 afE[4], afO[4], bfL[4], bfR[4];   // 16 short8 = 64 VGPR
  floatx4 acc[8][4];
#pragma unroll
  for (int i = 0; i < 8; i++)
#pragma unroll
    for (int j = 0; j < 4; j++)
      acc[i][j] = {0.f, 0.f, 0.f, 0.f};
  float rs[8] = {0.f, 0.f, 0.f, 0.f, 0.f, 0.f, 0.f, 0.f};   // MODE 2 only

#define SB __builtin_amdgcn_sched_barrier(0)
#define LG(N) { asm volatile("s_waitcnt lgkmcnt(" #N ")" ::: "memory"); SB; }
#define VM0   { asm volatile("s_waitcnt vmcnt(0)" ::: "memory"); SB; }

#define RD_AF(BANK, MP, CO)                                                   \
  { _Pragma("unroll")                                                         \
    for (int mi = 0; mi < 2; mi++) {                                          \
      BANK[mi*2+0] = *(const short8*)(As + (CO) + ((wm + (MP)*32 + mi*16 + lm) << 6) + ka0); \
      BANK[mi*2+1] = *(const short8*)(As + (CO) + ((wm + (MP)*32 + mi*16 + lm) << 6) + ka1); \
    } }
#define RD_BF(BANK, NH, CO)                                                   \
  { _Pragma("unroll")                                                         \
    for (int n = 0; n < 2; n++) {                                             \
      BANK[n*2+0] = *(const short8*)(Bs + (CO) + ((wn + (NH)*32 + n*16 + lm) << 6) + ka0); \
      BANK[n*2+1] = *(const short8*)(Bs + (CO) + ((wn + (NH)*32 + n*16 + lm) << 6) + ka1); \
    } }
#define SUMS(BANK, P)                                                         \
  if constexpr (MODE == 2) {                                                  \
    _Pragma("unroll")                                                         \
    for (int mi = 0; mi < 2; mi++)                                            \
      _Pragma("unroll")                                                       \
      for (int ks = 0; ks < 2; ks++) {                                        \
        uint4 u = *(const uint4*)&BANK[mi*2+ks];                              \
        rs[(P)*2+mi] +=                                                       \
            __uint_as_float(u.x << 16) + __uint_as_float(u.x & 0xffff0000u)   \
          + __uint_as_float(u.y << 16) + __uint_as_float(u.y & 0xffff0000u)   \
          + __uint_as_float(u.z << 16) + __uint_as_float(u.z & 0xffff0000u)   \
          + __uint_as_float(u.w << 16) + __uint_as_float(u.w & 0xffff0000u);  \
      } }
#define MM(MP, NH, AB, BB)                                                    \
  { __builtin_amdgcn_s_setprio(1);                                            \
    _Pragma("unroll")                                                         \
    for (int mi = 0; mi < 2; mi++)                                            \
      _Pragma("unroll")                                                       \
      for (int n = 0; n < 2; n++)                                             \
        _Pragma("unroll")                                                     \
        for (int ks = 0; ks < 2; ks++)                                        \
          acc[(MP)*2+mi][(NH)*2+n] = __builtin_amdgcn_mfma_f32_16x16x32_bf16( \
              AB[mi*2+ks], BB[n*2+ks], acc[(MP)*2+mi][(NH)*2+n], 0, 0, 0);    \
    __builtin_amdgcn_s_setprio(0); }

  const int NT = K >> 6;
  // prologue: stage tile 0 into buf 0 (8 loads); drain; collectivize.
  STG_A(0, 0, 0) STG_A(0, 0, 2) STG_B(0, 0, 0) STG_B(0, 0, 2)
  VM0;
  __builtin_amdgcn_s_barrier();

  for (int t = 0; t < NT; ++t) {
    const int co = (t & 1) * 16384;
    const int nbuf = (t & 1) ^ 1;
    const bool have = (t + 1 < NT);
    const int kn = (t + 1) << 6;

    // top-of-tile: issue first-phase frags (afE=m01, bfL) — 8 reads pending
    SB; RD_AF(afE, 0, co) RD_BF(bfL, 0, co) SB;
    // Ph0 (m01, L): +bfR; stage A[0:2]
    RD_BF(bfR, 1, co) if (have) STG_A(nbuf, kn, 0)
    LG(4) SUMS(afE, 0) MM(0, 0, afE, bfL) SB;
    // Ph1 (m01, R): +afO<-m23; stage A[2:4]
    RD_AF(afO, 1, co) if (have) STG_A(nbuf, kn, 2)
    LG(4) MM(0, 1, afE, bfR) SB;
    // Ph2 (m23, L): +afE<-m45; stage B[0:2]
    RD_AF(afE, 2, co) if (have) STG_B(nbuf, kn, 0)
    LG(4) SUMS(afO, 1) MM(1, 0, afO, bfL) SB;
    // Ph3 (m23, R): stage B[2:4]; no wait (afO,bfR already complete)
    if (have) STG_B(nbuf, kn, 2)
    MM(1, 1, afO, bfR) SB;
    // Ph4 (m45, L): +afO<-m67
    RD_AF(afO, 3, co)
    LG(4) SUMS(afE, 2) MM(2, 0, afE, bfL) SB;
    // Ph5 (m45, R): no issue, no wait
    MM(2, 1, afE, bfR) SB;
    // Ph6 (m67, L): drain all reads
    LG(0) SUMS(afO, 3) MM(3, 0, afO, bfL) SB;
    // Ph7 (m67, R)
    MM(3, 1, afO, bfR) SB;
    // tile end: t+1 stages resident collectively; fence next tile's stages
    VM0;
    __builtin_amdgcn_s_barrier();
  }
#undef MM
#undef SUMS
#undef RD_AF
#undef RD_BF
#undef LG
#undef VM0
#undef SB
#undef STG_A
#undef STG_B

  // C/D layout: col = lane&15, row = quad*4 + reg  [measured m89/m91]
  const int gm0 = tm * 256 + wm + quad * 4;
  const int gn0 = tn * 256 + wn + lm;
  const size_t cb = (size_t)bz * sC;

  if constexpr (MODE == 1) {
    const float* mrow = mask + (size_t)bz * LK_;
    bool msk[4];
#pragma unroll
    for (int ni = 0; ni < 4; ni++) msk[ni] = (mrow[gn0 + ni * 16] != 0.0f);
#pragma unroll
    for (int mi = 0; mi < 8; mi++) {
#pragma unroll
      for (int r = 0; r < 4; r++) {
        int row = gm0 + mi * 16 + r;
        size_t rowoff = cb + (size_t)row * ldc + gn0;
        float part = 0.f;
#pragma unroll
        for (int ni = 0; ni < 4; ni++) {
          float e = msk[ni] ? 0.f : __expf(acc[mi][ni][r]);
          u16 h = f2bf(e);
          ((u16*)C)[rowoff + ni * 16] = h;
          part += bf2f(h);   // sum the rounded value GEMM2 will actually use
        }
        if (denom) {
          part += __shfl_xor(part, 1, 64);
          part += __shfl_xor(part, 2, 64);
          part += __shfl_xor(part, 4, 64);
          part += __shfl_xor(part, 8, 64);
          if (lm == 0) atomicAdd(&denom[(size_t)bz * LQ_ + row], part);
        }
      }
    }
  } else if constexpr (MODE == 0) {
#pragma unroll
    for (int mi = 0; mi < 8; mi++) {
#pragma unroll
      for (int r = 0; r < 4; r++) {
        int row = gm0 + mi * 16 + r;
        float is = 1.0f / denom[(size_t)bz * LQ_ + row];
        size_t rowoff = cb + (size_t)row * ldc + gn0;
#pragma unroll
        for (int ni = 0; ni < 4; ni++)
          ((float*)C)[rowoff + ni * 16] = acc[mi][ni][r] * is;
      }
    }
  } else {  // MODE 2 fallback: finish in-loop rowsum
    float inv[8];
#pragma unroll
    for (int mi = 0; mi < 8; mi++) {
      rs[mi] += __shfl_xor(rs[mi], 16, 64);
      rs[mi] += __shfl_xor(rs[mi], 32, 64);
      inv[mi] = 1.0f / rs[mi];
    }
#pragma unroll
    for (int mi = 0; mi < 8; mi++) {
#pragma unroll
      for (int r = 0; r < 4; r++) {
        size_t rowoff = cb + (size_t)(gm0 + mi * 16 + r) * ldc + gn0;
        float is = __shfl(inv[mi], quad * 4 + r, 64);
#pragma unroll
        for (int ni = 0; ni < 4; ni++)
          ((float*)C)[rowoff + ni * 16] = acc[mi][ni][r] * is;
      }
    }
  }
}

// ---------------------------------------------------------------------------
// kernel_launch
// Inputs: 0=input [B,LQ,D] f32, 1=memory [B,LK,D] f32, 2=mask [B,LK] f32,
//         3=w_input [1,D] f32 (UNUSED: softmax is shift-invariant along k),
//         4=dot_scale [D] f32.
// Workspace layout (160 MB + 64 KB):
//   qb bf16 [B,LQ,D] @0 | mb bf16 [B,LK,D] @32MB | mbT bf16 [B,D,LK] @64MB
//   E bf16 [B,LQ,LK] @96MB | denom f32 [B,LQ] @160MB (if ws permits)
// ---------------------------------------------------------------------------
extern "C" void kernel_launch(void* const* d_in, const int* in_sizes, int n_in,
                              void* d_out, int out_size, void* d_ws, size_t ws_size,
                              hipStream_t stream) {
  const float* input  = (const float*)d_in[0];
  const float* memory = (const float*)d_in[1];
  const float* mask   = (const float*)d_in[2];
  const float* dscale = (const float*)d_in[4];

  char* ws = (char*)d_ws;
  u16* qb  = (u16*)(ws);
  u16* mb  = (u16*)(ws + (size_t)32 * 1024 * 1024);
  u16* mbT = (u16*)(ws + (size_t)64 * 1024 * 1024);
  u16* E   = (u16*)(ws + (size_t)96 * 1024 * 1024);
  size_t base = (size_t)160 * 1024 * 1024;
  bool have_denom = ws_size >= base + (size_t)B_ * LQ_ * sizeof(float);
  float* denom = have_denom ? (float*)(ws + base) : nullptr;
  float* out = (float*)d_out;

  hipLaunchKernelGGL(prep, dim3(32, 32, B_), dim3(256), 0, stream,
                     input, memory, dscale, qb, mb, mbT, denom);
  // E = exp(qb * mb^T), masked -> 0 : M=LQ, N=LK, K=D (+ denom accumulation)
  hipLaunchKernelGGL((gemm_bt<1>), dim3(LK_ / 256, LQ_ / 256, B_), dim3(512), 0,
                     stream, qb, mb, (void*)E, mask, denom, D_, D_, LK_,
                     (size_t)LQ_ * D_, (size_t)LK_ * D_, (size_t)LQ_ * LK_);
  // out = (E * mbT^T) / denom : M=LQ, N=D, K=LK
  if (have_denom)
    hipLaunchKernelGGL((gemm_bt<0>), dim3(D_ / 256, LQ_ / 256, B_), dim3(512), 0,
                       stream, E, mbT, (void*)out, nullptr, denom, LK_, LK_, D_,
                       (size_t)LQ_ * LK_, (size_t)D_ * LK_, (size_t)LQ_ * D_);
  else
    hipLaunchKernelGGL((gemm_bt<2>), dim3(D_ / 256, LQ_ / 256, B_), dim3(512), 0,
                       stream, E, mbT, (void*)out, nullptr, nullptr, LK_, LK_, D_,
                       (size_t)LQ_ * LK_, (size_t)D_ * LK_, (size_t)LQ_ * D_);
}

// Round 9
// 320.769 us; speedup vs baseline: 1.0032x; 1.0032x over previous
//
#include <hip/hip_runtime.h>

// Problem constants (B, LQ, LK, D from the reference)
#define B_  8
#define LQ_ 2048
#define LK_ 2048
#define D_  1024

typedef unsigned short u16;
using short8  = __attribute__((ext_vector_type(8))) short;   // 8 bf16 = 4 VGPRs (MFMA A/B frag)
using floatx4 = __attribute__((ext_vector_type(4))) float;   // MFMA C/D frag

#define GAS __attribute__((address_space(1)))
#define LAS __attribute__((address_space(3)))

__device__ __forceinline__ u16 f2bf(float f) {
  unsigned u = __float_as_uint(f);
  u += 0x7fffu + ((u >> 16) & 1u);   // round-to-nearest-even
  return (u16)(u >> 16);
}
__device__ __forceinline__ float bf2f(u16 h) {
  return __uint_as_float(((unsigned)h) << 16);
}

// ---------------------------------------------------------------------------
// prep (unchanged)
// ---------------------------------------------------------------------------
__global__ void prep(const float* __restrict__ in, const float* __restrict__ mem,
                     const float* __restrict__ ds, u16* __restrict__ qb,
                     u16* __restrict__ mb, u16* __restrict__ mbT,
                     float* __restrict__ denom) {
  __shared__ u16 tile[64][68];
  int tid = threadIdx.x;
  int tx = tid & 15, ty = tid >> 4;
  int b = blockIdx.z;

  if (denom && blockIdx.y == 16 && blockIdx.x == 0 && blockIdx.z == 0) {
    float4 z = {0.f, 0.f, 0.f, 0.f};
    float4* d4 = (float4*)denom;
#pragma unroll
    for (int i = 0; i < (B_ * LQ_ / 4) / 256; i++)
      d4[tid + i * 256] = z;
  }

  if (blockIdx.y < 16) {
    int k0 = blockIdx.x * 64, d0 = blockIdx.y * 64;
    const float* mB = mem + (size_t)b * LK_ * D_;
    u16* mbB = mb  + (size_t)b * LK_ * D_;
    u16* mtB = mbT + (size_t)b * D_ * LK_;
#pragma unroll
    for (int i = 0; i < 4; i++) {
      int r = ty + 16 * i;
      float4 v = *(const float4*)(mB + (size_t)(k0 + r) * D_ + d0 + tx * 4);
      ushort4 h;
      h.x = f2bf(v.x); h.y = f2bf(v.y); h.z = f2bf(v.z); h.w = f2bf(v.w);
      *(ushort4*)(mbB + (size_t)(k0 + r) * D_ + d0 + tx * 4) = h;
      *(ushort4*)(&tile[r][tx * 4]) = h;
    }
    __syncthreads();
#pragma unroll
    for (int i = 0; i < 4; i++) {
      int rr = ty + 16 * i;
      ushort4 o;
      o.x = tile[tx * 4 + 0][rr];
      o.y = tile[tx * 4 + 1][rr];
      o.z = tile[tx * 4 + 2][rr];
      o.w = tile[tx * 4 + 3][rr];
      *(ushort4*)(mtB + (size_t)(d0 + rr) * LK_ + k0 + tx * 4) = o;
    }
  } else {
    int q0 = blockIdx.x * 64, d0 = (blockIdx.y - 16) * 64;
    const float* iB = in + (size_t)b * LQ_ * D_;
    u16* qB = qb + (size_t)b * LQ_ * D_;
    float4 s4 = *(const float4*)(ds + d0 + tx * 4);
#pragma unroll
    for (int i = 0; i < 4; i++) {
      int r = ty + 16 * i;
      float4 v = *(const float4*)(iB + (size_t)(q0 + r) * D_ + d0 + tx * 4);
      ushort4 h;
      h.x = f2bf(v.x * s4.x); h.y = f2bf(v.y * s4.y);
      h.z = f2bf(v.z * s4.z); h.w = f2bf(v.w * s4.w);
      *(ushort4*)(qB + (size_t)(q0 + r) * D_ + d0 + tx * 4) = h;
    }
  }
}

// ---------------------------------------------------------------------------
// gemm_bt: C[M,N] = A[M,K] * B[N,K]^T per batch.
// GEOMETRY v8 (2 blocks/CU — the round-8 lesson):
//   Six schedule variants on the 256²/8-wave/128KiB-LDS geometry all landed
//   23-33% MfmaUtil: with 1 block/CU every wave shares one barrier, so all
//   resident waves stall together and no source schedule can create overlap.
//   v8 switches the overlap mechanism to INDEPENDENT BLOCKS (m97 mechanism):
//   tile 256Mx128N, BK=32, 256 threads = 4 waves (2Mx2N, wave tile 128x64,
//   ONE wave per SIMD). LDS = 2buf x (A 16K + B 8K) = 48 KiB -> 2 blocks/CU;
//   each SIMD hosts 2 waves from DIFFERENT blocks (different barriers):
//   when one block stalls (lgkm/vmcnt/barrier) the other issues MFMA.
//   Regs: acc[8][4] = 128 AGPR + ~90 arch <= 256 @ 2 waves/SIMD.
//   LDS swizzle (4 16B-slots/row): slot = chunk ^ (row&3), applied to the
//   global SOURCE of global_load_lds (dest linear) and the ds_read addr;
//   uniform 8 lanes per 16B slot across wave64 -> conflict-free.
// SCHEDULE (minimal, proven round-3 skeleton — no intra-tile finesse):
//   per K-tile: { ds_read bf[4]+af[8] (12 b128, cur); stage tile t+1 -> nb
//   (6 global_load_lds); lgkmcnt(0); setprio(1) 32 MFMA setprio(0);
//   vmcnt(0); s_barrier }.
//   ONE barrier/tile, AFTER both MFMA and the vm-drain: at the barrier every
//   wave has completed its reads (lgkm0 preceded its MFMA) and its stage
//   writes (vmcnt0) -> next tile's reads from nb and stages into cur are
//   both safe. Stage latency hides under the 32-MFMA cluster.
// MODE 1: score GEMM; E=exp(s) bf16 (masked->0) + atomic denom row sums.
// MODE 0: out GEMM; divides by denom[row], stores f32.
// MODE 2: fallback (in-loop rowsum from A fragments, no denom).
// ---------------------------------------------------------------------------
template <int MODE>
__global__ __launch_bounds__(256, 2) void gemm_bt(
    const u16* __restrict__ A, const u16* __restrict__ Bm,
    void* __restrict__ C, const float* __restrict__ mask,
    float* __restrict__ denom, int K, int ld, int ldc,
    size_t sA, size_t sB, size_t sC) {
  __shared__ __align__(16) u16 As[2 * 8192];   // [buf][256 rows][32 k] u16
  __shared__ __align__(16) u16 Bs[2 * 4096];   // [buf][128 rows][32 k] u16

  const int tid = threadIdx.x;
  const int lane = tid & 63, w = tid >> 6;
  const int lm = lane & 15, quad = (lane >> 4) & 3;
  const int wm = (w >> 1) * 128, wn = (w & 1) * 64;

  // ---- swizzle: batch = bid&7 (XCD affinity), GM=4 m-groups, n-fast ----
  const int tiles_n = gridDim.x;
  int bid = (blockIdx.z * gridDim.y + blockIdx.y) * tiles_n + blockIdx.x;
  int bz = bid & 7;
  int s = bid >> 3;
  const int GM = 4;
  int per_group = GM * tiles_n;
  int group = s / per_group;
  int rem = s - group * per_group;
  int tm = group * GM + (rem & (GM - 1));
  int tn = rem >> 2;

  const u16* Ab = A  + (size_t)bz * sA + (size_t)(tm * 256) * ld;
  const u16* Bb = Bm + (size_t)bz * sB + (size_t)(tn * 128) * ld;

  // ---- staging: A tile = 1024 16B-chunks (4/thread), B = 512 (2/thread).
  // chunk c: rho = c>>2 (row), sl = c&3 (slot). LDS dest linear (c*16 B);
  // global source pre-swizzled: k-chunk = sl ^ (rho&3).
  int goffA[4], goffB[2];
#pragma unroll
  for (int j = 0; j < 4; j++) {
    int c = tid + 256 * j;
    int rho = c >> 2, sl = c & 3;
    goffA[j] = rho * ld + (sl ^ (rho & 3)) * 8;   // elements
  }
#pragma unroll
  for (int j = 0; j < 2; j++) {
    int c = tid + 256 * j;
    int rho = c >> 2, sl = c & 3;
    goffB[j] = rho * ld + (sl ^ (rho & 3)) * 8;   // elements
  }

  auto stage = [&](int buf, int k0) {
#pragma unroll
    for (int j = 0; j < 4; j++)
      __builtin_amdgcn_global_load_lds(
          (GAS void*)(Ab + goffA[j] + k0),
          (LAS void*)(As + buf * 8192 + (tid + 256 * j) * 8), 16, 0, 0);
#pragma unroll
    for (int j = 0; j < 2; j++)
      __builtin_amdgcn_global_load_lds(
          (GAS void*)(Bb + goffB[j] + k0),
          (LAS void*)(Bs + buf * 4096 + (tid + 256 * j) * 8), 16, 0, 0);
  };

  // ---- fragment reads: logical k-chunk = quad at row (base16+lm);
  // swizzled slot = quad ^ (lm&3)  (row&3 == lm&3; bases are ×16).
  const int ka = (quad ^ (lm & 3)) * 8;

  short8 af[8], bf[4];
  floatx4 acc[8][4];
#pragma unroll
  for (int i = 0; i < 8; i++)
#pragma unroll
    for (int j = 0; j < 4; j++)
      acc[i][j] = {0.f, 0.f, 0.f, 0.f};
  float rs[8] = {0.f, 0.f, 0.f, 0.f, 0.f, 0.f, 0.f, 0.f};   // MODE 2 only

#define SB __builtin_amdgcn_sched_barrier(0)
#define LG0 { asm volatile("s_waitcnt lgkmcnt(0)" ::: "memory"); SB; }
#define VM0 { asm volatile("s_waitcnt vmcnt(0)" ::: "memory"); SB; }

  const int NT = K >> 5;
  // prologue: stage tile 0 into buf 0; drain; collectivize.
  stage(0, 0);
  VM0;
  __builtin_amdgcn_s_barrier();

  for (int t = 0; t < NT; ++t) {
    const int ca = (t & 1) * 8192;
    const int cbf = (t & 1) * 4096;
    const int nbuf = (t & 1) ^ 1;
    const bool have = (t + 1 < NT);
    const int kn = (t + 1) << 5;

    SB;
#pragma unroll
    for (int n = 0; n < 4; n++)
      bf[n] = *(const short8*)(Bs + cbf + ((wn + n * 16 + lm) << 5) + ka);
#pragma unroll
    for (int m = 0; m < 8; m++)
      af[m] = *(const short8*)(As + ca + ((wm + m * 16 + lm) << 5) + ka);
    if (have) stage(nbuf, kn);
    LG0;
    if constexpr (MODE == 2) {
#pragma unroll
      for (int m = 0; m < 8; m++) {
        uint4 u = *(const uint4*)&af[m];
        rs[m] += __uint_as_float(u.x << 16) + __uint_as_float(u.x & 0xffff0000u)
               + __uint_as_float(u.y << 16) + __uint_as_float(u.y & 0xffff0000u)
               + __uint_as_float(u.z << 16) + __uint_as_float(u.z & 0xffff0000u)
               + __uint_as_float(u.w << 16) + __uint_as_float(u.w & 0xffff0000u);
      }
    }
    __builtin_amdgcn_s_setprio(1);
#pragma unroll
    for (int m = 0; m < 8; m++)
#pragma unroll
      for (int n = 0; n < 4; n++)
        acc[m][n] = __builtin_amdgcn_mfma_f32_16x16x32_bf16(af[m], bf[n],
                                                            acc[m][n], 0, 0, 0);
    __builtin_amdgcn_s_setprio(0);
    SB;
    VM0;   // t+1 stages resident (hidden under the MFMA cluster)
    __builtin_amdgcn_s_barrier();
  }
#undef LG0
#undef VM0
#undef SB

  // C/D layout: col = lane&15, row = quad*4 + reg  [measured m89/m91]
  const int gm0 = tm * 256 + wm + quad * 4;
  const int gn0 = tn * 128 + wn + lm;
  const size_t cb = (size_t)bz * sC;

  if constexpr (MODE == 1) {
    const float* mrow = mask + (size_t)bz * LK_;
    bool msk[4];
#pragma unroll
    for (int ni = 0; ni < 4; ni++) msk[ni] = (mrow[gn0 + ni * 16] != 0.0f);
#pragma unroll
    for (int mi = 0; mi < 8; mi++) {
#pragma unroll
      for (int r = 0; r < 4; r++) {
        int row = gm0 + mi * 16 + r;
        size_t rowoff = cb + (size_t)row * ldc + gn0;
        float part = 0.f;
#pragma unroll
        for (int ni = 0; ni < 4; ni++) {
          float e = msk[ni] ? 0.f : __expf(acc[mi][ni][r]);
          u16 h = f2bf(e);
          ((u16*)C)[rowoff + ni * 16] = h;
          part += bf2f(h);   // sum the rounded value GEMM2 will actually use
        }
        if (denom) {
          part += __shfl_xor(part, 1, 64);
          part += __shfl_xor(part, 2, 64);
          part += __shfl_xor(part, 4, 64);
          part += __shfl_xor(part, 8, 64);
          if (lm == 0) atomicAdd(&denom[(size_t)bz * LQ_ + row], part);
        }
      }
    }
  } else if constexpr (MODE == 0) {
#pragma unroll
    for (int mi = 0; mi < 8; mi++) {
#pragma unroll
      for (int r = 0; r < 4; r++) {
        int row = gm0 + mi * 16 + r;
        float is = 1.0f / denom[(size_t)bz * LQ_ + row];
        size_t rowoff = cb + (size_t)row * ldc + gn0;
#pragma unroll
        for (int ni = 0; ni < 4; ni++)
          ((float*)C)[rowoff + ni * 16] = acc[mi][ni][r] * is;
      }
    }
  } else {  // MODE 2 fallback: finish in-loop rowsum
    float inv[8];
#pragma unroll
    for (int mi = 0; mi < 8; mi++) {
      rs[mi] += __shfl_xor(rs[mi], 16, 64);
      rs[mi] += __shfl_xor(rs[mi], 32, 64);
      inv[mi] = 1.0f / rs[mi];
    }
#pragma unroll
    for (int mi = 0; mi < 8; mi++) {
#pragma unroll
      for (int r = 0; r < 4; r++) {
        size_t rowoff = cb + (size_t)(gm0 + mi * 16 + r) * ldc + gn0;
        float is = __shfl(inv[mi], quad * 4 + r, 64);
#pragma unroll
        for (int ni = 0; ni < 4; ni++)
          ((float*)C)[rowoff + ni * 16] = acc[mi][ni][r] * is;
      }
    }
  }
}

// ---------------------------------------------------------------------------
// kernel_launch
// Inputs: 0=input [B,LQ,D] f32, 1=memory [B,LK,D] f32, 2=mask [B,LK] f32,
//         3=w_input [1,D] f32 (UNUSED: softmax is shift-invariant along k),
//         4=dot_scale [D] f32.
// Workspace layout (160 MB + 64 KB):
//   qb bf16 [B,LQ,D] @0 | mb bf16 [B,LK,D] @32MB | mbT bf16 [B,D,LK] @64MB
//   E bf16 [B,LQ,LK] @96MB | denom f32 [B,LQ] @160MB (if ws permits)
// ---------------------------------------------------------------------------
extern "C" void kernel_launch(void* const* d_in, const int* in_sizes, int n_in,
                              void* d_out, int out_size, void* d_ws, size_t ws_size,
                              hipStream_t stream) {
  const float* input  = (const float*)d_in[0];
  const float* memory = (const float*)d_in[1];
  const float* mask   = (const float*)d_in[2];
  const float* dscale = (const float*)d_in[4];

  char* ws = (char*)d_ws;
  u16* qb  = (u16*)(ws);
  u16* mb  = (u16*)(ws + (size_t)32 * 1024 * 1024);
  u16* mbT = (u16*)(ws + (size_t)64 * 1024 * 1024);
  u16* E   = (u16*)(ws + (size_t)96 * 1024 * 1024);
  size_t base = (size_t)160 * 1024 * 1024;
  bool have_denom = ws_size >= base + (size_t)B_ * LQ_ * sizeof(float);
  float* denom = have_denom ? (float*)(ws + base) : nullptr;
  float* out = (float*)d_out;

  hipLaunchKernelGGL(prep, dim3(32, 32, B_), dim3(256), 0, stream,
                     input, memory, dscale, qb, mb, mbT, denom);
  // E = exp(qb * mb^T), masked -> 0 : M=LQ, N=LK, K=D (+ denom accumulation)
  hipLaunchKernelGGL((gemm_bt<1>), dim3(LK_ / 128, LQ_ / 256, B_), dim3(256), 0,
                     stream, qb, mb, (void*)E, mask, denom, D_, D_, LK_,
                     (size_t)LQ_ * D_, (size_t)LK_ * D_, (size_t)LQ_ * LK_);
  // out = (E * mbT^T) / denom : M=LQ, N=D, K=LK
  if (have_denom)
    hipLaunchKernelGGL((gemm_bt<0>), dim3(D_ / 128, LQ_ / 256, B_), dim3(256), 0,
                       stream, E, mbT, (void*)out, nullptr, denom, LK_, LK_, D_,
                       (size_t)LQ_ * LK_, (size_t)D_ * LK_, (size_t)LQ_ * D_);
  else
    hipLaunchKernelGGL((gemm_bt<2>), dim3(D_ / 128, LQ_ / 256, B_), dim3(256), 0,
                       stream, E, mbT, (void*)out, nullptr, nullptr, LK_, LK_, D_,
                       (size_t)LQ_ * LK_, (size_t)D_ * LK_, (size_t)LQ_ * D_);
}